// Round 4
// baseline (45.678 us; speedup 1.0000x reference)
//
#include <hip/hip_runtime.h>

#define VOCAB 128000
#define HIST 512
#define ROW_F4 (VOCAB / 4)                 // 32000 float4 per row
#define CHUNKS_PER_ROW 8
#define CHUNK_F4 (ROW_F4 / CHUNKS_PER_ROW) // 4000 float4 per chunk
#define CHUNK_FLOATS (CHUNK_F4 * 4)        // 16000 floats per chunk

typedef float f32x4 __attribute__((ext_vector_type(4)));

// One block per (row, chunk): 256 rows x 8 chunks = 2048 blocks x 256 threads
// -> 8 blocks/CU, 32 waves/CU (the m13 copy-BW-saturating shape; VGPR=8).
// Phase 1: copy own chunk (16B vector loads, NT stores).
// Phase 2 (after __syncthreads, which drains vmcnt before the barrier): scan
// this row's pr save_ids and apply penalty only for indices inside own chunk
// -> copy/penalty WAW hazard stays intra-block, no second launch, no cross-
// block ordering assumption. Penalty reads ORIGINAL logits (duplicate ids
// write identical values).
__global__ __launch_bounds__(256)
void APPLY_PENALTY_5909874999394_fused(const f32x4* __restrict__ logits4,
                                       const float* __restrict__ logits,
                                       const int* __restrict__ save_id,
                                       const float* __restrict__ pval,
                                       const int* __restrict__ prange,
                                       f32x4* __restrict__ out4,
                                       float* __restrict__ out) {
    const int bid   = blockIdx.x;
    const int row   = bid >> 3;            // / CHUNKS_PER_ROW
    const int chunk = bid & 7;             // % CHUNKS_PER_ROW
    const long rowoff4 = (long)row * ROW_F4;
    const int  c0_4 = chunk * CHUNK_F4;

    // Phase 1: copy this chunk. 4000/256 = 15.6 iters/thread, coalesced.
    for (int j = threadIdx.x; j < CHUNK_F4; j += 256) {
        f32x4 v = logits4[rowoff4 + c0_4 + j];
        __builtin_nontemporal_store(v, &out4[rowoff4 + c0_4 + j]);
    }

    __syncthreads();  // s_waitcnt vmcnt(0) before s_barrier — chunk copy done

    // Phase 2: penalties landing in [lo, hi) of this row.
    const int pr = *prange;                // 64 at reference shapes
    const float p = *pval;
    const int lo = c0_4 * 4;
    const int hi = lo + CHUNK_FLOATS;
    const int base = row * HIST + (HIST - pr);
    const long rowoff = (long)row * VOCAB;
    for (int k = threadIdx.x; k < pr; k += 256) {
        const int idx = save_id[base + k];
        if (idx >= lo && idx < hi)
            out[rowoff + idx] = logits[rowoff + idx] * p;
    }
}

extern "C" void kernel_launch(void* const* d_in, const int* in_sizes, int n_in,
                              void* d_out, int out_size, void* d_ws, size_t ws_size,
                              hipStream_t stream) {
    const float* logits  = (const float*)d_in[0];
    const int*   save_id = (const int*)d_in[1];
    const float* pval    = (const float*)d_in[2];
    const int*   prange  = (const int*)d_in[3];
    float* out = (float*)d_out;

    const int rows = out_size / VOCAB;     // 256
    const int grid = rows * CHUNKS_PER_ROW; // 2048
    APPLY_PENALTY_5909874999394_fused<<<grid, 256, 0, stream>>>(
        (const f32x4*)logits, logits, save_id, pval, prange,
        (f32x4*)out, out);
}